// Round 6
// baseline (12421.964 us; speedup 1.0000x reference)
//
#include <hip/hip_runtime.h>

typedef unsigned long long u64;

#define M_ROWS 2048
#define N_COLS 4096
#define RHO_C 1.0f
#define STEP_C 5e-05f
#define MAX_ITERS_C 100
#define INNER_C 20

// ---- tagged 8B dataflow slots: (fp32 value | u32 tag) in one atomic ----
// Relaxed agent-scope 8B atomics are IC-coherent (bypass per-XCD L2 / L1);
// value+tag travel in ONE transaction -> no fences, no separate barrier.
__device__ __forceinline__ void slot_push(u64* p, float v, unsigned tag) {
    u64 val = ((u64)tag << 32) | (u64)__float_as_uint(v);
    __hip_atomic_store(p, val, __ATOMIC_RELAXED, __HIP_MEMORY_SCOPE_AGENT);
}
__device__ __forceinline__ u64 slot_ld(const u64* p) {
    return __hip_atomic_load(p, __ATOMIC_RELAXED, __HIP_MEMORY_SCOPE_AGENT);
}
__device__ __forceinline__ float4 slot_poll4(const u64* p, unsigned tag) {
    u64 a, b, c, d;
    for (;;) {
        a = slot_ld(p); b = slot_ld(p + 1);
        c = slot_ld(p + 2); d = slot_ld(p + 3);
        if (((unsigned)(a >> 32) == tag) & ((unsigned)(b >> 32) == tag) &
            ((unsigned)(c >> 32) == tag) & ((unsigned)(d >> 32) == tag))
            break;
        __builtin_amdgcn_s_sleep(1);
    }
    return make_float4(__uint_as_float((unsigned)a), __uint_as_float((unsigned)b),
                       __uint_as_float((unsigned)c), __uint_as_float((unsigned)d));
}
__device__ __forceinline__ float2 slot_poll2(const u64* p, unsigned tag) {
    u64 a, b;
    for (;;) {
        a = slot_ld(p); b = slot_ld(p + 1);
        if (((unsigned)(a >> 32) == tag) & ((unsigned)(b >> 32) == tag)) break;
        __builtin_amdgcn_s_sleep(1);
    }
    return make_float2(__uint_as_float((unsigned)a), __uint_as_float((unsigned)b));
}

// 256 blocks (1/CU) x 1024 threads (16 waves), persistent cooperative kernel.
// Gram form: g = c + rho*(M x - A^T rt), M = A^T A in registers:
// wave w=(cgp=w>>2, rq=w&3); accM[r][4q+e] = M[16b+4rq+r][1024cgp+256q+4l+e].
// Block b owns x entries [16b,16b+16) and rows [8b,8b+8) of A (Ax/s,u,rt).
// ALL cross-block exchange via tagged slots; NO grid barriers anywhere.
__global__ __launch_bounds__(1024) void admm_df(
    const float* __restrict__ A, const float* __restrict__ bvec,
    const float* __restrict__ cvec, float* __restrict__ out,
    u64* __restrict__ xslot,   // [2][4096] step-parity buffers
    u64* __restrict__ rslot,   // [2][2048] outer-parity buffers
    float* __restrict__ atp,   // optional packed A-columns, 32768 floats/block
    int use_packed)
{
    const int tid  = threadIdx.x;
    const int blk  = blockIdx.x;
    const int lane = tid & 63;
    const int wave = tid >> 6;
    const int cgp  = wave >> 2;
    const int rq   = wave & 3;

    __shared__ float  abuf[4 * N_COLS];  // 64 KB staging (A rows / rt / wred)
    __shared__ float4 xs4[1024];         // 16 KB staged x
    __shared__ float  red[4][16];
    __shared__ float4 gred[64];
    __shared__ float  wl[16], cw[16];
    __shared__ float  sv[8], uv[8], tpart[16];

    float* xs = reinterpret_cast<float*>(xs4);
    const float4* A4 = reinterpret_cast<const float4*>(A);
    float4* abuf4 = reinterpret_cast<float4*>(abuf);
    float* atpB = atp + (size_t)blk * 32768;

    // ---- init: publish own x (=0, tag 0) and rt (=b, tag 0) slots ----
    if (tid < 16) {
        cw[tid] = cvec[blk * 16 + tid];
        slot_push(&xslot[blk * 16 + tid], 0.0f, 0u);
    }
    if (tid < 8) {
        sv[tid] = 0.0f; uv[tid] = 0.0f;
        slot_push(&rslot[blk * 8 + tid], bvec[blk * 8 + tid], 0u);
    }

    // ---- precompute register-resident M fragment (block-local) ----
    float accM[4][16];
    #pragma unroll
    for (int r = 0; r < 4; ++r)
        #pragma unroll
        for (int k = 0; k < 16; ++k) accM[r][k] = 0.0f;

    for (int i0 = 0; i0 < M_ROWS; i0 += 4) {
        #pragma unroll
        for (int ii = 0; ii < 4; ++ii)
            abuf4[ii * 1024 + tid] = A4[(size_t)(i0 + ii) * 1024 + tid];
        __syncthreads();
        if (use_packed && tid < 64) {       // pack own 16 A-columns
            const int ii = tid >> 4, j = tid & 15;
            atpB[(i0 + ii) * 16 + j] = abuf[ii * N_COLS + blk * 16 + j];
        }
        #pragma unroll
        for (int ii = 0; ii < 4; ++ii) {
            const float*  row  = abuf + ii * N_COLS;
            const float4* row4 = abuf4 + ii * 1024;
            float4 av[4];
            #pragma unroll
            for (int q = 0; q < 4; ++q)
                av[q] = row4[256 * cgp + 64 * q + lane];
            float cb[4];
            #pragma unroll
            for (int r = 0; r < 4; ++r) cb[r] = row[blk * 16 + rq * 4 + r];
            #pragma unroll
            for (int r = 0; r < 4; ++r)
                #pragma unroll
                for (int q = 0; q < 4; ++q) {
                    accM[r][4*q+0] = fmaf(cb[r], av[q].x, accM[r][4*q+0]);
                    accM[r][4*q+1] = fmaf(cb[r], av[q].y, accM[r][4*q+1]);
                    accM[r][4*q+2] = fmaf(cb[r], av[q].z, accM[r][4*q+2]);
                    accM[r][4*q+3] = fmaf(cb[r], av[q].w, accM[r][4*q+3]);
                }
        }
        __syncthreads();
    }

    for (int outer = 0; outer < MAX_ITERS_C; ++outer) {
        // ---- stage rt (tag=outer) into abuf[0..2048) ----
        {
            const u64* rb = rslot + (outer & 1) * M_ROWS;
            float2 rv = slot_poll2(&rb[2 * tid], (unsigned)outer);
            abuf[2 * tid]     = rv.x;
            abuf[2 * tid + 1] = rv.y;
        }
        __syncthreads();

        // ---- w-phase: wl = (A^T rt)[16b..16b+16) ----
        if (use_packed) {
            const int rr = tid >> 4, j = tid & 15;
            float p = 0.f;
            #pragma unroll 4
            for (int k = 0; k < 32; ++k) {
                const int i = rr + (k << 6);
                p = fmaf(atpB[(i << 4) + j], abuf[i], p);
            }
            float* wred = abuf + 2048;
            wred[tid] = p;
            __syncthreads();
            if (tid < 256)
                wred[tid] = wred[tid] + wred[tid + 256]
                          + wred[tid + 512] + wred[tid + 768];
            __syncthreads();
            if (tid < 16) {
                float s = 0.f;
                #pragma unroll
                for (int r2 = 0; r2 < 16; ++r2) s += wred[r2 * 16 + tid];
                wl[tid] = s;
            }
        } else {
            const int p = tid >> 2, gq = tid & 3;
            float4 acc = {0.f, 0.f, 0.f, 0.f};
            #pragma unroll
            for (int k2 = 0; k2 < 8; ++k2) {
                const int i = p + 256 * k2;
                const float tv = abuf[i];
                float4 a = A4[(size_t)i * 1024 + blk * 4 + gq];
                acc.x = fmaf(a.x, tv, acc.x); acc.y = fmaf(a.y, tv, acc.y);
                acc.z = fmaf(a.z, tv, acc.z); acc.w = fmaf(a.w, tv, acc.w);
            }
            #pragma unroll
            for (int off = 4; off < 64; off <<= 1) {
                acc.x += __shfl_xor(acc.x, off);
                acc.y += __shfl_xor(acc.y, off);
                acc.z += __shfl_xor(acc.z, off);
                acc.w += __shfl_xor(acc.w, off);
            }
            if ((lane >> 2) == 0) gred[wave * 4 + gq] = acc;
            __syncthreads();
            if (tid < 4) {
                float4 tot = {0.f, 0.f, 0.f, 0.f};
                #pragma unroll
                for (int w = 0; w < 16; ++w) {
                    float4 v = gred[w * 4 + tid];
                    tot.x += v.x; tot.y += v.y; tot.z += v.z; tot.w += v.w;
                }
                wl[tid * 4 + 0] = tot.x; wl[tid * 4 + 1] = tot.y;
                wl[tid * 4 + 2] = tot.z; wl[tid * 4 + 3] = tot.w;
            }
        }
        __syncthreads();

        // ---- inner PGD: x <- relu(x - step*(c + rho*(Mx - wl))) ----
        for (int inner = 0; inner < INNER_C; ++inner) {
            const unsigned gs = (unsigned)(outer * INNER_C + inner);
            const u64* xrb = xslot + (gs & 1) * N_COLS;
            u64*       xwb = xslot + ((gs + 1) & 1) * N_COLS;

            // poll BEFORE touching xs4 (overlaps stragglers of prev step)
            float4 xv = slot_poll4(&xrb[4 * tid], gs);
            __syncthreads();          // prev step's xs readers done (WAR)
            xs4[tid] = xv;
            __syncthreads();

            float4 xq[4];
            #pragma unroll
            for (int q = 0; q < 4; ++q)
                xq[q] = xs4[256 * cgp + 64 * q + lane];

            float4 pd = {0.f, 0.f, 0.f, 0.f};
            #pragma unroll
            for (int q = 0; q < 4; ++q) {
                pd.x = fmaf(accM[0][4*q+0], xq[q].x, pd.x);
                pd.x = fmaf(accM[0][4*q+1], xq[q].y, pd.x);
                pd.x = fmaf(accM[0][4*q+2], xq[q].z, pd.x);
                pd.x = fmaf(accM[0][4*q+3], xq[q].w, pd.x);
                pd.y = fmaf(accM[1][4*q+0], xq[q].x, pd.y);
                pd.y = fmaf(accM[1][4*q+1], xq[q].y, pd.y);
                pd.y = fmaf(accM[1][4*q+2], xq[q].z, pd.y);
                pd.y = fmaf(accM[1][4*q+3], xq[q].w, pd.y);
                pd.z = fmaf(accM[2][4*q+0], xq[q].x, pd.z);
                pd.z = fmaf(accM[2][4*q+1], xq[q].y, pd.z);
                pd.z = fmaf(accM[2][4*q+2], xq[q].z, pd.z);
                pd.z = fmaf(accM[2][4*q+3], xq[q].w, pd.z);
                pd.w = fmaf(accM[3][4*q+0], xq[q].x, pd.w);
                pd.w = fmaf(accM[3][4*q+1], xq[q].y, pd.w);
                pd.w = fmaf(accM[3][4*q+2], xq[q].z, pd.w);
                pd.w = fmaf(accM[3][4*q+3], xq[q].w, pd.w);
            }
            #pragma unroll
            for (int off = 32; off; off >>= 1) {
                pd.x += __shfl_xor(pd.x, off);
                pd.y += __shfl_xor(pd.y, off);
                pd.z += __shfl_xor(pd.z, off);
                pd.w += __shfl_xor(pd.w, off);
            }
            if (lane == 0) {
                red[cgp][rq * 4 + 0] = pd.x;
                red[cgp][rq * 4 + 1] = pd.y;
                red[cgp][rq * 4 + 2] = pd.z;
                red[cgp][rq * 4 + 3] = pd.w;
            }
            __syncthreads();
            if (tid < 16) {
                const float y = red[0][tid] + red[1][tid]
                              + red[2][tid] + red[3][tid];
                const float g = cw[tid] + RHO_C * (y - wl[tid]);
                float xn = xs[blk * 16 + tid] - STEP_C * g;
                xn = xn > 0.f ? xn : 0.f;
                slot_push(&xwb[blk * 16 + tid], xn, gs + 1);
            }
            // no barrier: next step's poll IS the sync
        }

        // ---- Ax on own 8 rows + s,u,rt update ----
        {
            const unsigned tagAx = (unsigned)((outer + 1) * INNER_C);
            const u64* xrb = xslot + (tagAx & 1) * N_COLS;
            float4 xv = slot_poll4(&xrb[4 * tid], tagAx);
            __syncthreads();
            xs4[tid] = xv;
            __syncthreads();
        }
        {
            const int r = blk * 8 + (wave >> 1), h = wave & 1;
            const float4* Ar = A4 + (size_t)r * 1024 + h * 512;
            const float4* xh = xs4 + h * 512;
            float4 acc = {0.f, 0.f, 0.f, 0.f};
            #pragma unroll
            for (int it = 0; it < 8; ++it) {
                float4 a = Ar[it * 64 + lane], xv = xh[it * 64 + lane];
                acc.x = fmaf(a.x, xv.x, acc.x); acc.y = fmaf(a.y, xv.y, acc.y);
                acc.z = fmaf(a.z, xv.z, acc.z); acc.w = fmaf(a.w, xv.w, acc.w);
            }
            float d = acc.x + acc.y + acc.z + acc.w;
            #pragma unroll
            for (int off = 32; off; off >>= 1) d += __shfl_xor(d, off);
            if (lane == 0) tpart[wave] = d;
        }
        __syncthreads();
        if (tid < 8) {
            const int i = blk * 8 + tid;
            const float a  = tpart[2 * tid] + tpart[2 * tid + 1];
            const float bb = bvec[i];
            const float uu = uv[tid];
            float sn = a - bb + uu; sn = sn > 0.f ? sn : 0.f;
            const float un = uu + a - sn - bb;
            sv[tid] = sn; uv[tid] = un;
            slot_push(&rslot[((outer + 1) & 1) * M_ROWS + i],
                      sn + bb - un, (unsigned)(outer + 1));
        }
        __syncthreads();
    }

    // ---- outputs: [x(4096), s(2048), u(2048), -u(2048)] ----
    // xs still holds final x (staged for the last Ax phase).
    if (tid < 16) out[blk * 16 + tid] = xs[blk * 16 + tid];
    if (tid < 8) {
        const int i = blk * 8 + tid;
        out[4096 + i] = sv[tid];
        out[6144 + i] = uv[tid];
        out[8192 + i] = -uv[tid];
    }
}

extern "C" void kernel_launch(void* const* d_in, const int* in_sizes, int n_in,
                              void* d_out, int out_size, void* d_ws, size_t ws_size,
                              hipStream_t stream) {
    const float* A    = (const float*)d_in[0];   // 2048*4096
    const float* bvec = (const float*)d_in[1];   // 2048
    const float* cvec = (const float*)d_in[2];   // 4096
    float* out = (float*)d_out;

    char* ws = (char*)d_ws;
    u64*   xslot = (u64*)(ws);                 // 2*4096*8B = 64 KiB
    u64*   rslot = (u64*)(ws + 65536);         // 2*2048*8B = 32 KiB
    float* atp   = (float*)(ws + 131072);      // 256*32768*4B = 32 MiB (optional)
    int use_packed = (ws_size >= (size_t)131072 + (size_t)256 * 32768 * 4) ? 1 : 0;

    void* args[] = { (void*)&A, (void*)&bvec, (void*)&cvec, (void*)&out,
                     (void*)&xslot, (void*)&rslot, (void*)&atp,
                     (void*)&use_packed };
    hipError_t err = hipLaunchCooperativeKernel((const void*)admm_df,
                               dim3(256), dim3(1024), args, 0, stream);
    (void)err;
}

// Round 7
// 11939.780 us; speedup vs baseline: 1.0404x; 1.0404x over previous
//
#include <hip/hip_runtime.h>
#include <hip/hip_cooperative_groups.h>

namespace cg = cooperative_groups;
typedef unsigned int u32;

#define M_ROWS 2048
#define N_COLS 4096
#define RHO_C 1.0f
#define STEP_C 5e-05f
#define MAX_ITERS_C 100
#define INNER_C 20

// Relaxed agent-scope atomics: coherent at the Infinity Cache (sc1 path),
// bypassing per-XCD L2 / per-CU L1. Validated by R4/R5/R6 correctness.
__device__ __forceinline__ float aload(const float* p) {
    return __hip_atomic_load(p, __ATOMIC_RELAXED, __HIP_MEMORY_SCOPE_AGENT);
}
__device__ __forceinline__ void astore(float* p, float v) {
    __hip_atomic_store(p, v, __ATOMIC_RELAXED, __HIP_MEMORY_SCOPE_AGENT);
}
__device__ __forceinline__ float2 aload2(const float* p) {
    unsigned long long v = __hip_atomic_load(
        (const unsigned long long*)p, __ATOMIC_RELAXED,
        __HIP_MEMORY_SCOPE_AGENT);
    union { unsigned long long u; float2 f; } c; c.u = v; return c.f;
}
__device__ __forceinline__ u32 aloadu(const u32* p) {
    return __hip_atomic_load(p, __ATOMIC_RELAXED, __HIP_MEMORY_SCOPE_AGENT);
}
__device__ __forceinline__ void astoreu(u32* p, u32 v) {
    __hip_atomic_store(p, v, __ATOMIC_RELAXED, __HIP_MEMORY_SCOPE_AGENT);
}

// Wave-0-only poll: lane l watches tags[4l..4l+3] until ALL 256 tags >= need.
// Tags are monotonic (no wrap below 2001) -> min-compare is safe.
__device__ __forceinline__ void poll256(const u32* tags, u32 need, int lane) {
    const u32* p = tags + 4 * lane;
    for (;;) {
        u32 t0 = aloadu(p);     u32 t1 = aloadu(p + 1);
        u32 t2 = aloadu(p + 2); u32 t3 = aloadu(p + 3);
        u32 mn = t0 < t1 ? t0 : t1;
        u32 mn2 = t2 < t3 ? t2 : t3;
        mn = mn < mn2 ? mn : mn2;
        if (__ballot(mn < need) == 0ull) return;
        __builtin_amdgcn_s_sleep(1);
    }
}

// 256 blocks (1/CU) x 1024 threads (16 waves), persistent cooperative kernel.
// Gram form: g = c + rho*(M x - A^T rt), M = A^T A in registers:
// wave w=(cgp=w>>2, rq=w&3); accM[r][4q+e] = M[16b+4rq+r][1024cgp+256q+4l+e].
// Block b owns x entries [16b,16b+16) and rows [8b,8b+8) of A (Ax/s,u,rt).
// Sync = per-block monotonic tags: data astores -> __syncthreads (drains
// vmcnt -> stores acked at IC) -> one tag astore. Consumers poll tags with
// wave 0 only, then aload data. No RMW barriers anywhere after init.
__global__ __launch_bounds__(1024) void admm_tag(
    const float* __restrict__ A, const float* __restrict__ bvec,
    const float* __restrict__ cvec, float* __restrict__ out,
    float* __restrict__ xbuf,   // [2][4096] step-parity x buffers
    float* __restrict__ rtb,    // [2][2048] outer-parity rt buffers
    u32* __restrict__ xtag,     // [256] x states produced per block
    u32* __restrict__ rtag)     // [256] rt states produced per block
{
    cg::grid_group grid = cg::this_grid();
    const int tid  = threadIdx.x;
    const int blk  = blockIdx.x;
    const int lane = tid & 63;
    const int wave = tid >> 6;
    const int cgp  = wave >> 2;
    const int rq   = wave & 3;

    __shared__ float  abuf[4 * N_COLS];  // 64 KB staging (A rows / rt)
    __shared__ float4 xs4[1024];         // 16 KB staged x
    __shared__ float  red[4][16];
    __shared__ float4 gred[64];
    __shared__ float  wl[16], cw[16];
    __shared__ float  sv[8], uv[8], tpart[16];

    float* xs = reinterpret_cast<float*>(xs4);
    const float4* A4 = reinterpret_cast<const float4*>(A);
    float4* abuf4 = reinterpret_cast<float4*>(abuf);

    // ---- init: local state + zero own tags (published by the one cg sync) ----
    if (tid < 16) cw[tid] = cvec[blk * 16 + tid];
    if (tid < 8) { sv[tid] = 0.0f; uv[tid] = 0.0f; }
    if (tid == 0) { astoreu(&xtag[blk], 0u); astoreu(&rtag[blk], 0u); }

    // ---- precompute register-resident M fragment (block-local) ----
    float accM[4][16];
    #pragma unroll
    for (int r = 0; r < 4; ++r)
        #pragma unroll
        for (int k = 0; k < 16; ++k) accM[r][k] = 0.0f;

    for (int i0 = 0; i0 < M_ROWS; i0 += 4) {
        #pragma unroll
        for (int ii = 0; ii < 4; ++ii)
            abuf4[ii * 1024 + tid] = A4[(size_t)(i0 + ii) * 1024 + tid];
        __syncthreads();
        #pragma unroll
        for (int ii = 0; ii < 4; ++ii) {
            const float*  row  = abuf + ii * N_COLS;
            const float4* row4 = abuf4 + ii * 1024;
            float4 av[4];
            #pragma unroll
            for (int q = 0; q < 4; ++q)
                av[q] = row4[256 * cgp + 64 * q + lane];
            float cb[4];
            #pragma unroll
            for (int r = 0; r < 4; ++r) cb[r] = row[blk * 16 + rq * 4 + r];
            #pragma unroll
            for (int r = 0; r < 4; ++r)
                #pragma unroll
                for (int q = 0; q < 4; ++q) {
                    accM[r][4*q+0] = fmaf(cb[r], av[q].x, accM[r][4*q+0]);
                    accM[r][4*q+1] = fmaf(cb[r], av[q].y, accM[r][4*q+1]);
                    accM[r][4*q+2] = fmaf(cb[r], av[q].z, accM[r][4*q+2]);
                    accM[r][4*q+3] = fmaf(cb[r], av[q].w, accM[r][4*q+3]);
                }
        }
        __syncthreads();
    }

    grid.sync();   // one cg sync: tags (=0) now globally visible

    for (int outer = 0; outer < MAX_ITERS_C; ++outer) {
        // ---- stage rt(state=outer) into abuf[0..2048) ----
        if (outer == 0) {
            abuf[2 * tid]     = bvec[2 * tid];
            abuf[2 * tid + 1] = bvec[2 * tid + 1];
        } else {
            if (wave == 0) poll256(rtag, (u32)outer, lane);
            __syncthreads();
            const float* rb = rtb + (outer & 1) * M_ROWS;
            float2 rv = aload2(rb + 2 * tid);
            abuf[2 * tid]     = rv.x;
            abuf[2 * tid + 1] = rv.y;
        }
        __syncthreads();

        // ---- w-phase: wl = (A^T rt)[16b..16b+16) ----
        {
            const int p = tid >> 2, gq = tid & 3;
            float4 acc = {0.f, 0.f, 0.f, 0.f};
            #pragma unroll
            for (int k2 = 0; k2 < 8; ++k2) {
                const int i = p + 256 * k2;
                const float tv = abuf[i];
                float4 a = A4[(size_t)i * 1024 + blk * 4 + gq];
                acc.x = fmaf(a.x, tv, acc.x); acc.y = fmaf(a.y, tv, acc.y);
                acc.z = fmaf(a.z, tv, acc.z); acc.w = fmaf(a.w, tv, acc.w);
            }
            #pragma unroll
            for (int off = 4; off < 64; off <<= 1) {
                acc.x += __shfl_xor(acc.x, off);
                acc.y += __shfl_xor(acc.y, off);
                acc.z += __shfl_xor(acc.z, off);
                acc.w += __shfl_xor(acc.w, off);
            }
            if ((lane >> 2) == 0) gred[wave * 4 + gq] = acc;
        }
        __syncthreads();
        if (tid < 4) {
            float4 tot = {0.f, 0.f, 0.f, 0.f};
            #pragma unroll
            for (int w = 0; w < 16; ++w) {
                float4 v = gred[w * 4 + tid];
                tot.x += v.x; tot.y += v.y; tot.z += v.z; tot.w += v.w;
            }
            wl[tid * 4 + 0] = tot.x; wl[tid * 4 + 1] = tot.y;
            wl[tid * 4 + 2] = tot.z; wl[tid * 4 + 3] = tot.w;
        }
        __syncthreads();

        // ---- inner PGD: x <- relu(x - step*(c + rho*(Mx - wl))) ----
        for (int inner = 0; inner < INNER_C; ++inner) {
            const u32 gs = (u32)(outer * INNER_C + inner);  // state consumed

            if (outer == 0 && inner == 0) {
                xs4[tid] = make_float4(0.f, 0.f, 0.f, 0.f);
                __syncthreads();
            } else if (inner > 0) {
                if (wave == 0) poll256(xtag, gs, lane);
                __syncthreads();    // releases waves; prev xs4 readers done
                const float* xb = xbuf + (gs & 1) * N_COLS;
                float2 lo = aload2(xb + 4 * tid);
                float2 hi = aload2(xb + 4 * tid + 2);
                xs4[tid] = make_float4(lo.x, lo.y, hi.x, hi.y);
                __syncthreads();
            }
            // inner==0 && outer>0: xs4 already holds state gs (Ax staging)

            float4 xq[4];
            #pragma unroll
            for (int q = 0; q < 4; ++q)
                xq[q] = xs4[256 * cgp + 64 * q + lane];

            float4 pd = {0.f, 0.f, 0.f, 0.f};
            #pragma unroll
            for (int q = 0; q < 4; ++q) {
                pd.x = fmaf(accM[0][4*q+0], xq[q].x, pd.x);
                pd.x = fmaf(accM[0][4*q+1], xq[q].y, pd.x);
                pd.x = fmaf(accM[0][4*q+2], xq[q].z, pd.x);
                pd.x = fmaf(accM[0][4*q+3], xq[q].w, pd.x);
                pd.y = fmaf(accM[1][4*q+0], xq[q].x, pd.y);
                pd.y = fmaf(accM[1][4*q+1], xq[q].y, pd.y);
                pd.y = fmaf(accM[1][4*q+2], xq[q].z, pd.y);
                pd.y = fmaf(accM[1][4*q+3], xq[q].w, pd.y);
                pd.z = fmaf(accM[2][4*q+0], xq[q].x, pd.z);
                pd.z = fmaf(accM[2][4*q+1], xq[q].y, pd.z);
                pd.z = fmaf(accM[2][4*q+2], xq[q].z, pd.z);
                pd.z = fmaf(accM[2][4*q+3], xq[q].w, pd.z);
                pd.w = fmaf(accM[3][4*q+0], xq[q].x, pd.w);
                pd.w = fmaf(accM[3][4*q+1], xq[q].y, pd.w);
                pd.w = fmaf(accM[3][4*q+2], xq[q].z, pd.w);
                pd.w = fmaf(accM[3][4*q+3], xq[q].w, pd.w);
            }
            #pragma unroll
            for (int off = 32; off; off >>= 1) {
                pd.x += __shfl_xor(pd.x, off);
                pd.y += __shfl_xor(pd.y, off);
                pd.z += __shfl_xor(pd.z, off);
                pd.w += __shfl_xor(pd.w, off);
            }
            if (lane == 0) {
                red[cgp][rq * 4 + 0] = pd.x;
                red[cgp][rq * 4 + 1] = pd.y;
                red[cgp][rq * 4 + 2] = pd.z;
                red[cgp][rq * 4 + 3] = pd.w;
            }
            __syncthreads();

            if (tid < 16) {
                const float y = red[0][tid] + red[1][tid]
                              + red[2][tid] + red[3][tid];
                const float g = cw[tid] + RHO_C * (y - wl[tid]);
                float xn = xs[blk * 16 + tid] - STEP_C * g;
                xn = xn > 0.f ? xn : 0.f;
                astore(&xbuf[((gs + 1) & 1) * N_COLS + blk * 16 + tid], xn);
            }
            __syncthreads();     // drains vmcnt -> x stores acked at IC
            if (tid == 0) astoreu(&xtag[blk], gs + 1);   // release tag
        }

        // ---- Ax phase: needs x state gsf = (outer+1)*INNER_C ----
        {
            const u32 gsf = (u32)((outer + 1) * INNER_C);
            if (wave == 0) poll256(xtag, gsf, lane);
            __syncthreads();
            const float* xb = xbuf + (gsf & 1) * N_COLS;
            float2 lo = aload2(xb + 4 * tid);
            float2 hi = aload2(xb + 4 * tid + 2);
            xs4[tid] = make_float4(lo.x, lo.y, hi.x, hi.y);
            __syncthreads();
        }
        {
            const int r = blk * 8 + (wave >> 1), h = wave & 1;
            const float4* Ar = A4 + (size_t)r * 1024 + h * 512;
            const float4* xh = xs4 + h * 512;
            float4 acc = {0.f, 0.f, 0.f, 0.f};
            #pragma unroll
            for (int it = 0; it < 8; ++it) {
                float4 a = Ar[it * 64 + lane], xv = xh[it * 64 + lane];
                acc.x = fmaf(a.x, xv.x, acc.x); acc.y = fmaf(a.y, xv.y, acc.y);
                acc.z = fmaf(a.z, xv.z, acc.z); acc.w = fmaf(a.w, xv.w, acc.w);
            }
            float d = acc.x + acc.y + acc.z + acc.w;
            #pragma unroll
            for (int off = 32; off; off >>= 1) d += __shfl_xor(d, off);
            if (lane == 0) tpart[wave] = d;
        }
        __syncthreads();
        if (tid < 8) {
            const int i = blk * 8 + tid;
            const float a  = tpart[2 * tid] + tpart[2 * tid + 1];
            const float bb = bvec[i];
            const float uu = uv[tid];
            float sn = a - bb + uu; sn = sn > 0.f ? sn : 0.f;
            const float un = uu + a - sn - bb;
            sv[tid] = sn; uv[tid] = un;
            astore(&rtb[((outer + 1) & 1) * M_ROWS + i], sn + bb - un);
        }
        __syncthreads();     // drains rt stores
        if (tid == 0) astoreu(&rtag[blk], (u32)(outer + 1));
    }

    // ---- outputs: [x(4096), s(2048), u(2048), -u(2048)] ----
    // xs4 holds final x (state 2000, staged in the last Ax phase).
    if (tid < 16) out[blk * 16 + tid] = xs[blk * 16 + tid];
    if (tid < 8) {
        const int i = blk * 8 + tid;
        out[4096 + i] = sv[tid];
        out[6144 + i] = uv[tid];
        out[8192 + i] = -uv[tid];
    }
}

extern "C" void kernel_launch(void* const* d_in, const int* in_sizes, int n_in,
                              void* d_out, int out_size, void* d_ws, size_t ws_size,
                              hipStream_t stream) {
    const float* A    = (const float*)d_in[0];   // 2048*4096
    const float* bvec = (const float*)d_in[1];   // 2048
    const float* cvec = (const float*)d_in[2];   // 4096
    float* out = (float*)d_out;

    float* ws   = (float*)d_ws;
    float* xbuf = ws;                       // 2*4096 floats
    float* rtb  = ws + 8192;                // 2*2048 floats
    u32*   xtag = (u32*)(ws + 12288);       // 256 u32
    u32*   rtag = (u32*)(ws + 12288 + 256); // 256 u32

    void* args[] = { (void*)&A, (void*)&bvec, (void*)&cvec, (void*)&out,
                     (void*)&xbuf, (void*)&rtb, (void*)&xtag, (void*)&rtag };
    hipError_t err = hipLaunchCooperativeKernel((const void*)admm_tag,
                               dim3(256), dim3(1024), args, 0, stream);
    (void)err;
}

// Round 8
// 11432.669 us; speedup vs baseline: 1.0865x; 1.0444x over previous
//
#include <hip/hip_runtime.h>
#include <hip/hip_cooperative_groups.h>

namespace cg = cooperative_groups;
typedef unsigned int u32;
typedef unsigned long long u64;

#define M_ROWS 2048
#define N_COLS 4096
#define RHO_C 1.0f
#define STEP_C 5e-05f
#define MAX_ITERS_C 100
#define INNER_C 20

// Relaxed agent-scope atomics: IC-coherent, bypass L1/per-XCD L2.
// Correctness of this model validated by R4-R7 (absmax stable 0.0078).
__device__ __forceinline__ u64 ald64(const u64* p) {
    return __hip_atomic_load(p, __ATOMIC_RELAXED, __HIP_MEMORY_SCOPE_AGENT);
}
__device__ __forceinline__ void ast64(u64* p, u64 v) {
    __hip_atomic_store(p, v, __ATOMIC_RELAXED, __HIP_MEMORY_SCOPE_AGENT);
}
// Fused (value,tag) slot: one 8B atom -> publish and detect in a single hop
// each way. Exact-tag match: 0xAA poison never equals a live tag (<= 2001),
// so no initialization and no grid.sync are needed anywhere.
__device__ __forceinline__ void push_slot(u64* p, float v, u32 tag) {
    ast64(p, ((u64)tag << 32) | (u64)__float_as_uint(v));
}
__device__ __forceinline__ float4 poll4(const u64* p, u32 tag) {
    for (;;) {
        u64 a = ald64(p),     b = ald64(p + 1);
        u64 c = ald64(p + 2), d = ald64(p + 3);
        if (((u32)(a >> 32) == tag) & ((u32)(b >> 32) == tag) &
            ((u32)(c >> 32) == tag) & ((u32)(d >> 32) == tag))
            return make_float4(__uint_as_float((u32)a), __uint_as_float((u32)b),
                               __uint_as_float((u32)c), __uint_as_float((u32)d));
        __builtin_amdgcn_s_sleep(1);
    }
}
__device__ __forceinline__ float2 poll2(const u64* p, u32 tag) {
    for (;;) {
        u64 a = ald64(p), b = ald64(p + 1);
        if (((u32)(a >> 32) == tag) & ((u32)(b >> 32) == tag))
            return make_float2(__uint_as_float((u32)a), __uint_as_float((u32)b));
        __builtin_amdgcn_s_sleep(1);
    }
}

// 256 blocks (1/CU) x 1024 threads (16 waves), persistent cooperative kernel.
// Gram form: g = c + rho*(M x - A^T rt), M = A^T A in registers:
// wave w=(cgp=w>>2, rq=w&3); accM[r][4q+e] = M[16b+4rq+r][1024cgp+256q+4l+e].
// Block b owns x entries [16b,16b+16) and rows [8b,8b+8) of A (Ax/s,u,rt).
// Exchange = push-broadcast: producer writes fused slots into `fanout`
// mailbox copies; consumer (copy = blk&7) polls its own copy's lines.
// xmb layout: [copy][parity][4096] u64.  rmb: [copy][parity][2048] u64.
__global__ __launch_bounds__(1024) void admm_push(
    const float* __restrict__ A, const float* __restrict__ bvec,
    const float* __restrict__ cvec, float* __restrict__ out,
    u64* __restrict__ xmb, u64* __restrict__ rmb, int fanout)
{
    const int tid  = threadIdx.x;
    const int blk  = blockIdx.x;
    const int lane = tid & 63;
    const int wave = tid >> 6;
    const int cgp  = wave >> 2;
    const int rq   = wave & 3;
    const int cpy  = (fanout == 1) ? 0 : (blk & 7);

    __shared__ float  abuf[4 * N_COLS];  // 64 KB staging (A rows / rt)
    __shared__ float4 xs4[1024];         // 16 KB staged x
    __shared__ float  red[4][16];
    __shared__ float4 gred[64];
    __shared__ float  wl[16], cw[16];
    __shared__ float  sv[8], uv[8], tpart[16], rtnew[8];

    float* xs = reinterpret_cast<float*>(xs4);
    const float4* A4 = reinterpret_cast<const float4*>(A);
    float4* abuf4 = reinterpret_cast<float4*>(abuf);
    const u64* xmyc = xmb + (size_t)cpy * 8192;   // my x mailbox copy
    const u64* rmyc = rmb + (size_t)cpy * 4096;   // my rt mailbox copy

    if (tid < 16) cw[tid] = cvec[blk * 16 + tid];
    if (tid < 8) { sv[tid] = 0.0f; uv[tid] = 0.0f; }

    // ---- precompute register-resident M fragment (block-local) ----
    float accM[4][16];
    #pragma unroll
    for (int r = 0; r < 4; ++r)
        #pragma unroll
        for (int k = 0; k < 16; ++k) accM[r][k] = 0.0f;

    for (int i0 = 0; i0 < M_ROWS; i0 += 4) {
        #pragma unroll
        for (int ii = 0; ii < 4; ++ii)
            abuf4[ii * 1024 + tid] = A4[(size_t)(i0 + ii) * 1024 + tid];
        __syncthreads();
        #pragma unroll
        for (int ii = 0; ii < 4; ++ii) {
            const float*  row  = abuf + ii * N_COLS;
            const float4* row4 = abuf4 + ii * 1024;
            float4 av[4];
            #pragma unroll
            for (int q = 0; q < 4; ++q)
                av[q] = row4[256 * cgp + 64 * q + lane];
            float cb[4];
            #pragma unroll
            for (int r = 0; r < 4; ++r) cb[r] = row[blk * 16 + rq * 4 + r];
            #pragma unroll
            for (int r = 0; r < 4; ++r)
                #pragma unroll
                for (int q = 0; q < 4; ++q) {
                    accM[r][4*q+0] = fmaf(cb[r], av[q].x, accM[r][4*q+0]);
                    accM[r][4*q+1] = fmaf(cb[r], av[q].y, accM[r][4*q+1]);
                    accM[r][4*q+2] = fmaf(cb[r], av[q].z, accM[r][4*q+2]);
                    accM[r][4*q+3] = fmaf(cb[r], av[q].w, accM[r][4*q+3]);
                }
        }
        __syncthreads();
    }
    // no grid.sync needed: tags are exact-match, poison never matches

    for (int outer = 0; outer < MAX_ITERS_C; ++outer) {
        // ---- stage rt(state=outer) into abuf[0..2048) ----
        if (outer == 0) {
            abuf[2 * tid]     = bvec[2 * tid];
            abuf[2 * tid + 1] = bvec[2 * tid + 1];
        } else {
            float2 rv = poll2(rmyc + (outer & 1) * 2048 + 2 * tid, (u32)outer);
            abuf[2 * tid]     = rv.x;
            abuf[2 * tid + 1] = rv.y;
        }
        __syncthreads();

        // ---- w-phase: wl = (A^T rt)[16b..16b+16) ----
        {
            const int p = tid >> 2, gq = tid & 3;
            float4 acc = {0.f, 0.f, 0.f, 0.f};
            #pragma unroll
            for (int k2 = 0; k2 < 8; ++k2) {
                const int i = p + 256 * k2;
                const float tv = abuf[i];
                float4 a = A4[(size_t)i * 1024 + blk * 4 + gq];
                acc.x = fmaf(a.x, tv, acc.x); acc.y = fmaf(a.y, tv, acc.y);
                acc.z = fmaf(a.z, tv, acc.z); acc.w = fmaf(a.w, tv, acc.w);
            }
            #pragma unroll
            for (int off = 4; off < 64; off <<= 1) {
                acc.x += __shfl_xor(acc.x, off);
                acc.y += __shfl_xor(acc.y, off);
                acc.z += __shfl_xor(acc.z, off);
                acc.w += __shfl_xor(acc.w, off);
            }
            if ((lane >> 2) == 0) gred[wave * 4 + gq] = acc;
        }
        __syncthreads();
        if (tid < 4) {
            float4 tot = {0.f, 0.f, 0.f, 0.f};
            #pragma unroll
            for (int w = 0; w < 16; ++w) {
                float4 v = gred[w * 4 + tid];
                tot.x += v.x; tot.y += v.y; tot.z += v.z; tot.w += v.w;
            }
            wl[tid * 4 + 0] = tot.x; wl[tid * 4 + 1] = tot.y;
            wl[tid * 4 + 2] = tot.z; wl[tid * 4 + 3] = tot.w;
        }
        __syncthreads();

        // ---- inner PGD: x <- relu(x - step*(c + rho*(Mx - wl))) ----
        for (int inner = 0; inner < INNER_C; ++inner) {
            const u32 gs = (u32)(outer * INNER_C + inner);  // state consumed

            if (gs == 0) {
                xs4[tid] = make_float4(0.f, 0.f, 0.f, 0.f);
                __syncthreads();
            } else if (inner > 0) {
                // fused poll: detect + data in the same loads
                float4 xv = poll4(xmyc + (gs & 1) * 4096 + 4 * tid, gs);
                __syncthreads();   // S2: all local pushers/readers of old state done
                xs4[tid] = xv;
                __syncthreads();   // S3: staged
            }
            // inner==0 && outer>0: xs4 already holds state gs (Ax staging)

            float4 xq[4];
            #pragma unroll
            for (int q = 0; q < 4; ++q)
                xq[q] = xs4[256 * cgp + 64 * q + lane];

            float4 pd = {0.f, 0.f, 0.f, 0.f};
            #pragma unroll
            for (int q = 0; q < 4; ++q) {
                pd.x = fmaf(accM[0][4*q+0], xq[q].x, pd.x);
                pd.x = fmaf(accM[0][4*q+1], xq[q].y, pd.x);
                pd.x = fmaf(accM[0][4*q+2], xq[q].z, pd.x);
                pd.x = fmaf(accM[0][4*q+3], xq[q].w, pd.x);
                pd.y = fmaf(accM[1][4*q+0], xq[q].x, pd.y);
                pd.y = fmaf(accM[1][4*q+1], xq[q].y, pd.y);
                pd.y = fmaf(accM[1][4*q+2], xq[q].z, pd.y);
                pd.y = fmaf(accM[1][4*q+3], xq[q].w, pd.y);
                pd.z = fmaf(accM[2][4*q+0], xq[q].x, pd.z);
                pd.z = fmaf(accM[2][4*q+1], xq[q].y, pd.z);
                pd.z = fmaf(accM[2][4*q+2], xq[q].z, pd.z);
                pd.z = fmaf(accM[2][4*q+3], xq[q].w, pd.z);
                pd.w = fmaf(accM[3][4*q+0], xq[q].x, pd.w);
                pd.w = fmaf(accM[3][4*q+1], xq[q].y, pd.w);
                pd.w = fmaf(accM[3][4*q+2], xq[q].z, pd.w);
                pd.w = fmaf(accM[3][4*q+3], xq[q].w, pd.w);
            }
            #pragma unroll
            for (int off = 32; off; off >>= 1) {
                pd.x += __shfl_xor(pd.x, off);
                pd.y += __shfl_xor(pd.y, off);
                pd.z += __shfl_xor(pd.z, off);
                pd.w += __shfl_xor(pd.w, off);
            }
            if (lane == 0) {
                red[cgp][rq * 4 + 0] = pd.x;
                red[cgp][rq * 4 + 1] = pd.y;
                red[cgp][rq * 4 + 2] = pd.z;
                red[cgp][rq * 4 + 3] = pd.w;
            }
            __syncthreads();     // S1: red ready

            // push: each pusher recomputes the update redundantly (no serial
            // tid<16 section, no extra barrier) and stores fused (val,tag).
            if (tid < fanout * 16) {
                const int dst = tid >> 4, jj = tid & 15;
                const float y = red[0][jj] + red[1][jj]
                              + red[2][jj] + red[3][jj];
                const float g = cw[jj] + RHO_C * (y - wl[jj]);
                float xn = xs[blk * 16 + jj] - STEP_C * g;
                xn = xn > 0.f ? xn : 0.f;
                push_slot(xmb + (size_t)dst * 8192 + ((gs + 1) & 1) * 4096
                              + blk * 16 + jj, xn, gs + 1);
            }
            // no drain, no tag store: next iteration's poll IS the sync
        }

        // ---- Ax phase: needs x state gsf = (outer+1)*INNER_C ----
        {
            const u32 gsf = (u32)((outer + 1) * INNER_C);
            float4 xv = poll4(xmyc + (gsf & 1) * 4096 + 4 * tid, gsf);
            __syncthreads();
            xs4[tid] = xv;
            __syncthreads();
        }
        {
            const int r = blk * 8 + (wave >> 1), h = wave & 1;
            const float4* Ar = A4 + (size_t)r * 1024 + h * 512;
            const float4* xh = xs4 + h * 512;
            float4 acc = {0.f, 0.f, 0.f, 0.f};
            #pragma unroll
            for (int it = 0; it < 8; ++it) {
                float4 a = Ar[it * 64 + lane], xv = xh[it * 64 + lane];
                acc.x = fmaf(a.x, xv.x, acc.x); acc.y = fmaf(a.y, xv.y, acc.y);
                acc.z = fmaf(a.z, xv.z, acc.z); acc.w = fmaf(a.w, xv.w, acc.w);
            }
            float d = acc.x + acc.y + acc.z + acc.w;
            #pragma unroll
            for (int off = 32; off; off >>= 1) d += __shfl_xor(d, off);
            if (lane == 0) tpart[wave] = d;
        }
        __syncthreads();
        if (tid < 8) {
            const int i = blk * 8 + tid;
            const float a  = tpart[2 * tid] + tpart[2 * tid + 1];
            const float bb = bvec[i];
            const float uu = uv[tid];
            float sn = a - bb + uu; sn = sn > 0.f ? sn : 0.f;
            const float un = uu + a - sn - bb;
            sv[tid] = sn; uv[tid] = un;
            rtnew[tid] = sn + bb - un;
        }
        __syncthreads();
        if (tid < fanout * 8) {
            const int dst = tid >> 3, jj = tid & 7;
            push_slot(rmb + (size_t)dst * 4096 + ((outer + 1) & 1) * 2048
                          + blk * 8 + jj, rtnew[jj], (u32)(outer + 1));
        }
    }

    // ---- outputs: [x(4096), s(2048), u(2048), -u(2048)] ----
    // xs4 holds final x (state 2000, staged in the last Ax phase).
    if (tid < 16) out[blk * 16 + tid] = xs[blk * 16 + tid];
    if (tid < 8) {
        const int i = blk * 8 + tid;
        out[4096 + i] = sv[tid];
        out[6144 + i] = uv[tid];
        out[8192 + i] = -uv[tid];
    }
}

extern "C" void kernel_launch(void* const* d_in, const int* in_sizes, int n_in,
                              void* d_out, int out_size, void* d_ws, size_t ws_size,
                              hipStream_t stream) {
    const float* A    = (const float*)d_in[0];   // 2048*4096
    const float* bvec = (const float*)d_in[1];   // 2048
    const float* cvec = (const float*)d_in[2];   // 4096
    float* out = (float*)d_out;

    // fanout=8: xmb 8*8192*8B = 512 KiB, rmb 8*4096*8B = 256 KiB (768 KiB).
    // fanout=1 fallback (R6-equivalent shared slots): 96 KiB.
    int fanout = (ws_size >= (size_t)(1 << 20)) ? 8 : 1;
    u64* xmb = (u64*)d_ws;
    u64* rmb = xmb + (size_t)fanout * 8192;

    void* args[] = { (void*)&A, (void*)&bvec, (void*)&cvec, (void*)&out,
                     (void*)&xmb, (void*)&rmb, (void*)&fanout };
    hipError_t err = hipLaunchCooperativeKernel((const void*)admm_push,
                               dim3(256), dim3(1024), args, 0, stream);
    (void)err;
}